// Round 6
// baseline (181.439 us; speedup 1.0000x reference)
//
#include <hip/hip_runtime.h>
#include <hip/hip_bf16.h>

#define NUM_CLASSES 100000
#define DIM 256
#define BATCH 256
#define NUM_TRUE 1024
#define NUM_SAMPLED 16384
// ln(NUM_CLASSES + 1)
#define LOG_RANGE 11.51293546492023f
#define INV_LOG_RANGE (1.0f / LOG_RANGE)

#define SBLOCKS 512   // sampled blocks (32 s-rows each), scheduled FIRST
#define TBLOCKS 2048  // true blocks (128 labels each)

typedef __bf16 bf16x8 __attribute__((ext_vector_type(8)));
typedef float  f32x4  __attribute__((ext_vector_type(4)));

// RNE float -> bf16 bits
static __device__ __forceinline__ unsigned short f2bf(float f) {
    unsigned int u = __float_as_uint(f);
    unsigned int lsb = (u >> 16) & 1u;
    u += 0x7fffu + lsb;
    return (unsigned short)(u >> 16);
}

// -log(expected_count(id)) inline, fast-math formulation.
// p via log1pf(1/(id+1)) keeps p to ~1e-7 rel (avoids 1+eps quantization);
// -log1p(-p) ~= p(1 + p/2 + p^2/3), p <= 0.0603 -> rel err ~5e-5;
// ec = 1 - exp(-S q): cancellation-safe in our range (S q >= 0.014).
static __device__ __forceinline__ float neg_log_ec_fast(int id) {
    float idf = (float)id;
    float e = 1.0f / (idf + 1.0f);
    float p = log1pf(e) * INV_LOG_RANGE;
    float q = p * (1.0f + 0.5f * p + 0.3333333f * p * p);
    float ec = 1.0f - __expf(-(float)NUM_SAMPLED * q);
    return -__logf(ec);
}

static __device__ __forceinline__ float dot4(float4 a, float4 b) {
    return fmaf(a.x, b.x, fmaf(a.y, b.y, fmaf(a.z, b.z, a.w * b.w)));
}

// ---------------- inputs fp32 -> bf16 (into workspace) ----------------
__global__ __launch_bounds__(256) void conv_kernel(const float* __restrict__ in,
                                                   unsigned short* __restrict__ out) {
    int idx = blockIdx.x * 256 + threadIdx.x;   // 16384 float4s
    float4 v = ((const float4*)in)[idx];
    ushort4 p;
    p.x = f2bf(v.x); p.y = f2bf(v.y); p.z = f2bf(v.z); p.w = f2bf(v.w);
    ((ushort4*)out)[idx] = p;
}

// ---------------- fused kernel: sampled blocks first, then true ----------------
// LDS ~19.6 KB -> 8 blocks/CU; sampled MFMA hides under true's memory waits.
__global__ __launch_bounds__(256) void fused_kernel(const float* __restrict__ inputs,
                                                    const float* __restrict__ w,
                                                    const float* __restrict__ bias,
                                                    const int* __restrict__ labels,
                                                    const int* __restrict__ sampled,
                                                    const unsigned short* __restrict__ inbf,
                                                    float* __restrict__ truep,
                                                    float* __restrict__ partial) {
    __shared__ unsigned short lw[32][264];   // w s-tile, bf16 (16.9 KB)
    __shared__ float cs[32];
    __shared__ float bacc[BATCH];
    __shared__ __align__(16) float ins[DIM];
    __shared__ float wsum[4];

    const int tid = threadIdx.x;

    if (blockIdx.x < SBLOCKS) {
        // ================= sampled path: 32 s-rows x 256 batch =================
        const int sblk = blockIdx.x;
        const int s0 = sblk * 32;
        bacc[tid] = 0.0f;

        // stage 32 w rows -> bf16 LDS (per wave-load: 4 rows x 256B = 16 lines)
        const int inner = tid & 15;
        const int r16   = tid >> 4;
        #pragma unroll
        for (int rb = 0; rb < 2; ++rb) {
            const int r = rb * 16 + r16;
            const int id = sampled[s0 + r];
            const float* src = w + (size_t)id * DIM;
            #pragma unroll
            for (int j = 0; j < 4; ++j) {
                float4 v = *(const float4*)(src + j * 64 + inner * 4);
                ushort4 pk;
                pk.x = f2bf(v.x); pk.y = f2bf(v.y); pk.z = f2bf(v.z); pk.w = f2bf(v.w);
                *(ushort4*)(&lw[r][j * 64 + inner * 4]) = pk;
            }
        }
        if (tid < 32) {
            const int id = sampled[s0 + tid];
            cs[tid] = bias[id] + neg_log_ec_fast(id);
        }
        __syncthreads();

        const int lane = tid & 63;
        const int wv   = tid >> 6;
        const int m    = lane & 15;
        const int quad = lane >> 4;
        const int shalf = (wv >> 1) * 16;    // which 16 s-rows
        const int bhalf = (wv & 1) * 128;    // which 128 batch cols

        // A-fragments for this wave's 16 s-rows, all K: 32 VGPRs, persistent
        bf16x8 af[8];
        #pragma unroll
        for (int kk = 0; kk < 8; ++kk)
            af[kk] = *(const bf16x8*)(&lw[shalf + m][kk * 32 + quad * 8]);

        #pragma unroll
        for (int t = 0; t < 8; ++t) {
            const int brow = bhalf + t * 16 + m;
            const unsigned short* bp = inbf + brow * DIM;
            bf16x8 bf[8];
            #pragma unroll
            for (int kk = 0; kk < 8; ++kk)
                bf[kk] = *(const bf16x8*)(bp + kk * 32 + quad * 8);
            f32x4 acc = {0, 0, 0, 0};
            #pragma unroll
            for (int kk = 0; kk < 8; ++kk)
                acc = __builtin_amdgcn_mfma_f32_16x16x32_bf16(af[kk], bf[kk], acc, 0, 0, 0);
            // C/D: row(s) = quad*4 + r, col(b) = m
            float ps = 0.0f;
            #pragma unroll
            for (int r = 0; r < 4; ++r) {
                float c = cs[shalf + quad * 4 + r];
                float l = acc[r] + c;
                ps += fmaxf(l, 0.0f) + __logf(1.0f + __expf(-fabsf(l)));
            }
            ps += __shfl_xor(ps, 16); ps += __shfl_xor(ps, 32);
            if (quad == 0) atomicAdd(&bacc[bhalf + t * 16 + m], ps);
        }
        __syncthreads();
        partial[tid * SBLOCKS + sblk] = bacc[tid];   // [b][sblk]
    } else {
        // ================= true path: 16 lanes/label, depth-2 pipeline =========
        const int bid  = blockIdx.x - SBLOCKS;
        const int b    = bid >> 3;
        const int chnk = bid & 7;
        ins[tid] = inputs[b * DIM + tid];
        __syncthreads();

        const int lane = tid & 63;
        const int wv   = tid >> 6;
        const int sub  = lane >> 4;
        const int part = lane & 15;
        const float4* ir = (const float4*)ins;
        const float4 in0 = ir[part], in1 = ir[16 + part], in2 = ir[32 + part], in3 = ir[48 + part];

        const int* lab = labels + b * NUM_TRUE + chnk * 128 + wv * 32;

        float4 buf[2][4];
        float  cb[2];
        #pragma unroll
        for (int s = 0; s < 2; ++s) {
            int l = lab[s * 4 + sub];
            const float4* wr = (const float4*)(w + (size_t)l * DIM);
            buf[s][0] = wr[part];      buf[s][1] = wr[16 + part];
            buf[s][2] = wr[32 + part]; buf[s][3] = wr[48 + part];
            cb[s] = bias[l] + neg_log_ec_fast(l);
        }

        float acc = 0.0f;
        #pragma unroll
        for (int i = 0; i < 8; ++i) {
            const int cur = i & 1;
            float4 w0 = buf[cur][0], w1 = buf[cur][1], w2 = buf[cur][2], w3 = buf[cur][3];
            float cl = cb[cur];
            if (i < 6) {   // refill the consumed slot two iterations ahead
                int l = lab[(i + 2) * 4 + sub];
                const float4* wr = (const float4*)(w + (size_t)l * DIM);
                buf[cur][0] = wr[part];      buf[cur][1] = wr[16 + part];
                buf[cur][2] = wr[32 + part]; buf[cur][3] = wr[48 + part];
                cb[cur] = bias[l] + neg_log_ec_fast(l);
            }
            float d = dot4(w0, in0) + dot4(w1, in1) + dot4(w2, in2) + dot4(w3, in3);
            d += __shfl_xor(d, 1); d += __shfl_xor(d, 2);
            d += __shfl_xor(d, 4); d += __shfl_xor(d, 8);
            float logit = d + cl;
            float v = fmaxf(logit, 0.0f) - logit * (1.0f / (float)NUM_TRUE)
                    + __logf(1.0f + __expf(-fabsf(logit)));
            acc += (part == 0) ? v : 0.0f;
        }
        acc += __shfl_xor(acc, 16); acc += __shfl_xor(acc, 32);
        if (lane == 0) wsum[wv] = acc;
        __syncthreads();
        if (tid == 0) truep[b * 8 + chnk] = wsum[0] + wsum[1] + wsum[2] + wsum[3];
    }
}

// ---- final reduce: out[b] = sum_512 sampled partials + sum_8 true partials ----
__global__ __launch_bounds__(256) void reduce_kernel(const float* __restrict__ partial,
                                                     const float* __restrict__ truep,
                                                     float* __restrict__ out) {
    __shared__ float wsum[4];
    const int b = blockIdx.x;
    const int tid = threadIdx.x;
    float v = partial[b * SBLOCKS + tid] + partial[b * SBLOCKS + 256 + tid];
    if (tid < 8) v += truep[b * 8 + tid];
    v += __shfl_xor(v, 1);  v += __shfl_xor(v, 2);  v += __shfl_xor(v, 4);
    v += __shfl_xor(v, 8);  v += __shfl_xor(v, 16); v += __shfl_xor(v, 32);
    if ((tid & 63) == 0) wsum[tid >> 6] = v;
    __syncthreads();
    if (tid == 0) out[b] = wsum[0] + wsum[1] + wsum[2] + wsum[3];
}

extern "C" void kernel_launch(void* const* d_in, const int* in_sizes, int n_in,
                              void* d_out, int out_size, void* d_ws, size_t ws_size,
                              hipStream_t stream) {
    const float* inputs  = (const float*)d_in[0];   // [256,256]
    const float* w       = (const float*)d_in[1];   // [100000,256]
    const float* bias    = (const float*)d_in[2];   // [100000]
    const int*   labels  = (const int*)d_in[3];     // [256,1024]
    const int*   sampled = (const int*)d_in[4];     // [16384]
    float* out = (float*)d_out;                     // [256]

    unsigned short* inbf    = (unsigned short*)d_ws;            // 128 KB
    float*          truep   = (float*)((char*)d_ws + 131072);   // 8 KB
    float*          partial = (float*)((char*)d_ws + 139264);   // 512 KB

    conv_kernel<<<64, 256, 0, stream>>>(inputs, inbf);
    fused_kernel<<<SBLOCKS + TBLOCKS, 256, 0, stream>>>(inputs, w, bias, labels,
                                                        sampled, inbf, truep, partial);
    reduce_kernel<<<BATCH, 256, 0, stream>>>(partial, truep, out);
}